// Round 7
// baseline (157.662 us; speedup 1.0000x reference)
//
#include <hip/hip_runtime.h>

typedef unsigned short u16;
typedef unsigned int u32;
typedef __bf16 bf16x8 __attribute__((ext_vector_type(8)));
typedef float f32x16 __attribute__((ext_vector_type(16)));

#define C2 (-7.213475204444817f) /* -5/ln2 : exp(-5 t^2) = exp2(C2 t^2) */
#define T1C 0.28650480f          /* e^-1.25 */
#define T2C 0.0067379470f        /* e^-5    */

__device__ __forceinline__ u16 f2bf(float f) {
  u32 u = __float_as_uint(f);
  return (u16)((u + 0x7FFFu + ((u >> 16) & 1u)) >> 16);  // RNE
}

__device__ __forceinline__ void async16(const void* g, void* l) {
  __builtin_amdgcn_global_load_lds(
      (const __attribute__((address_space(1))) u32*)g,
      (__attribute__((address_space(3))) u32*)l, 16, 0, 0);
}

__device__ __forceinline__ f32x16 mfma16(uint4 a, uint4 b, f32x16 c) {
  return __builtin_amdgcn_mfma_f32_32x32x16_bf16(
      __builtin_bit_cast(bf16x8, a), __builtin_bit_cast(bf16x8, b), c, 0, 0, 0);
}

// ---------------------------------------------------------------------------
// Prep: f32 weights -> bf16 in PER-16K-CHUNK FRAGMENT ORDER.
// wst3 granule(c, g) 16 B, g = s*256 + nq*64 + l:
//   content = W_s[k = c*16 + (l>>5)*8 + 0..8)[u = nq*32 + (l&31)]
//   (s = 0..4 spline grid g, s = 5 base weight)
// grid 64 (one block per 16-k chunk), 256 threads.
// ---------------------------------------------------------------------------
__global__ __launch_bounds__(256) void kan_prep(const float* __restrict__ wb,
                                                const float* __restrict__ ws,
                                                u16* __restrict__ wst3) {
  __shared__ u16 tile[6][16][130];  // [s][d][u], pad 130 (d-stride = bank+1)
  const int t = threadIdx.x;
  const int c = blockIdx.x;
#pragma unroll
  for (int it = 0; it < 8; ++it) {
    int idx = it * 256 + t;
    int d = idx >> 7, u = idx & 127;
    size_t base = (size_t)(c * 16 + d) * 128 + u;
    const float* p = ws + base * 8;
    float4 v0 = *(const float4*)p;  // grid 0..3
    float g4 = p[4];
    tile[0][d][u] = f2bf(v0.x);
    tile[1][d][u] = f2bf(v0.y);
    tile[2][d][u] = f2bf(v0.z);
    tile[3][d][u] = f2bf(v0.w);
    tile[4][d][u] = f2bf(g4);
    tile[5][d][u] = f2bf(wb[base]);
  }
  __syncthreads();
#pragma unroll
  for (int i = 0; i < 6; ++i) {
    int g = i * 256 + t;            // 1536 granules per chunk
    int s = g >> 8, r = g & 255;
    int nq = r >> 6, l = r & 63;
    int u = nq * 32 + (l & 31);
    int dbase = (l >> 5) * 8;
    u32 q[4];
#pragma unroll
    for (int j = 0; j < 4; ++j) {
      u32 lo = tile[s][dbase + 2 * j][u];
      u32 hi = tile[s][dbase + 2 * j + 1][u];
      q[j] = lo | (hi << 16);
    }
    uint4 w4; w4.x = q[0]; w4.y = q[1]; w4.z = q[2]; w4.w = q[3];
    *(uint4*)(wst3 + (size_t)c * 12288 + (size_t)g * 8) = w4;
  }
}

// ---------------------------------------------------------------------------
// Main. grid 256, block 512 = 8 waves (wm, wn, kks), tile M=64 N=128.
// BK=16 chunks (64 of them); wave kks consumes only chunks with c&1==kks
// (k-partition; partials merged in LDS epilogue). Buffer = 36 KB
// (As 12 KB @0, Bs 24 KB @12288), dbuf = 72 KB -> 2 blocks/CU, 4 waves/SIMD:
// the co-resident block covers barrier drains (the R2-R6 serialization).
// As granule: byte = s*2048 + g*1024 + l*16, A[m=(l&31)+32g][k=(l>>5)*8+j].
//   Writers: wave w writes per sub one contiguous 256-B run at s*2048+w*256
//   + lane*4 (conflict-free); thread owns x row (lp&31)+32*(w>>2),
//   k = (lp>>5)*8+(lane&3)*2 (+0,1), lp = (w&3)*16+(lane>>2).
// Bs granule: byte = 12288 + s*4096 + nq*1024 + l*16 (DMA linear src+dst).
// mfma A[m=lane&31][k=(lane>>5)*8+j]; C/D col=lane&31,
// row=(reg&3)+8*(reg>>2)+4*(lane>>5)   (validated R2-R6).
// ---------------------------------------------------------------------------
__global__ __launch_bounds__(512, 4) void kan_main(const float* __restrict__ x,
                                                   const u16* __restrict__ wst3,
                                                   float* __restrict__ out) {
  __shared__ __align__(16) char lds[73728];  // 2 x 36864

  const int t = threadIdx.x;
  const int lane = t & 63;
  const int w = t >> 6;           // 0..7
  const int wm = (w >> 2) & 1, wn = (w >> 1) & 1, kks = w & 1;
  const int b0 = blockIdx.x * 64;
  const int kh = lane >> 5;

  f32x16 accs[2], accb[2];
#pragma unroll
  for (int i = 0; i < 16; ++i) {
    accs[0][i] = 0.f; accs[1][i] = 0.f;
    accb[0][i] = 0.f; accb[1][i] = 0.f;
  }

  // ---- rbf writer mapping (one contiguous 256-B run per wave per sub)
  const int lp = (w & 3) * 16 + (lane >> 2);
  const int wrow = (lp & 31) + 32 * (w >> 2);
  const int wk = (lp >> 5) * 8 + (lane & 3) * 2;
  const float* xp = x + (size_t)(b0 + wrow) * 1024 + wk;
  const u32 aw = (u32)(w * 256 + lane * 4);  // + s*2048

  // ---- DMA: fully linear; granule g = i*512 + t
  const char* dsrc = (const char*)wst3 + t * 16;

  // ---- reader offsets
  const u32 ao = (u32)(wm * 1024 + lane * 16);            // + s*2048
  const u32 bo = (u32)(12288 + wn * 2048 + lane * 16);    // + s*4096 (+1024 nt=1)

  auto dma = [&](int c, char* buf) {
    const char* s0 = dsrc + (size_t)c * 24576;
    char* d0 = buf + 12288 + t * 16;
#pragma unroll
    for (int i = 0; i < 3; ++i) async16(s0 + i * 8192, d0 + i * 8192);
  };

  auto rbf_write = [&](char* buf, float2 xa) {
    float xf[2] = {xa.x, xa.y};
    u32 rb[6][2];
#pragma unroll
    for (int e = 0; e < 2; ++e) {
      float xv = xf[e];
      float t0 = C2 * xv;
      float P = __builtin_amdgcn_exp2f(t0 * xv);  // e^{-5x^2}
      float Qp = __builtin_amdgcn_exp2f(-t0);     // e^{+5x}
      float Qm = __builtin_amdgcn_exp2f(t0);      // e^{-5x}
      float PQ = P * Qp, PQm = P * Qm;
      rb[0][e] = __float_as_uint(PQm * Qm * T2C) + 0x8000u;
      rb[1][e] = __float_as_uint(PQm * T1C) + 0x8000u;
      rb[2][e] = __float_as_uint(P) + 0x8000u;
      rb[3][e] = __float_as_uint(PQ * T1C) + 0x8000u;
      rb[4][e] = __float_as_uint(PQ * Qp * T2C) + 0x8000u;
      rb[5][e] = __float_as_uint(xv) + 0x8000u;
    }
#pragma unroll
    for (int s = 0; s < 6; ++s) {
      u32 pk = __builtin_amdgcn_perm(rb[s][1], rb[s][0], 0x07060302);
      *(u32*)(buf + s * 2048 + aw) = pk;
    }
  };

  // ---- pipeline
  float2 xc = *(const float2*)(xp);       // k-chunk 0
  dma(0, lds);
  rbf_write(lds, xc);
  float2 xn = *(const float2*)(xp + 16);  // k-chunk 1
  __syncthreads();

  for (int c = 0; c < 64; ++c) {
    char* cur = lds + (size_t)(c & 1) * 36864;
    if (c < 63) {
      char* nxt = lds + (size_t)((c + 1) & 1) * 36864;
      dma(c + 1, nxt);                    // async, drained at this barrier
      rbf_write(nxt, xn);
      if (c < 62) xn = *(const float2*)(xp + (c + 2) * 16);
    }
    if ((c & 1) == kks) {                 // wave-uniform branch
#pragma unroll
      for (int s = 0; s < 6; ++s) {
        uint4 a  = *(const uint4*)(cur + s * 2048 + ao);
        uint4 v0 = *(const uint4*)(cur + s * 4096 + bo);
        uint4 v1 = *(const uint4*)(cur + s * 4096 + bo + 1024);
        if (s < 5) {
          accs[0] = mfma16(a, v0, accs[0]);
          accs[1] = mfma16(a, v1, accs[1]);
        } else {
          accb[0] = mfma16(a, v0, accb[0]);
          accb[1] = mfma16(a, v1, accb[1]);
        }
      }
    }
    __syncthreads();
  }

  // ---- epilogue: merge kks partials via LDS, silu(base)+spline, f32 stores
  const int pw = w ^ 1;  // partner wave (other kks)
#pragma unroll
  for (int q = 0; q < 4; ++q) {
    {
      float4 s0 = make_float4(accs[0][4 * q], accs[0][4 * q + 1], accs[0][4 * q + 2], accs[0][4 * q + 3]);
      float4 s1 = make_float4(accs[1][4 * q], accs[1][4 * q + 1], accs[1][4 * q + 2], accs[1][4 * q + 3]);
      float4 b0v = make_float4(accb[0][4 * q], accb[0][4 * q + 1], accb[0][4 * q + 2], accb[0][4 * q + 3]);
      float4 b1v = make_float4(accb[1][4 * q], accb[1][4 * q + 1], accb[1][4 * q + 2], accb[1][4 * q + 3]);
      *(float4*)(lds + (w * 4 + 0) * 1024 + lane * 16) = s0;
      *(float4*)(lds + (w * 4 + 1) * 1024 + lane * 16) = s1;
      *(float4*)(lds + (w * 4 + 2) * 1024 + lane * 16) = b0v;
      *(float4*)(lds + (w * 4 + 3) * 1024 + lane * 16) = b1v;
    }
    __syncthreads();
    if (kks == 0) {
      float4 ps0 = *(const float4*)(lds + (pw * 4 + 0) * 1024 + lane * 16);
      float4 ps1 = *(const float4*)(lds + (pw * 4 + 1) * 1024 + lane * 16);
      float4 pb0 = *(const float4*)(lds + (pw * 4 + 2) * 1024 + lane * 16);
      float4 pb1 = *(const float4*)(lds + (pw * 4 + 3) * 1024 + lane * 16);
      const float* ps0f = &ps0.x; const float* ps1f = &ps1.x;
      const float* pb0f = &pb0.x; const float* pb1f = &pb1.x;
#pragma unroll
      for (int rr = 0; rr < 4; ++rr) {
        int reg = 4 * q + rr;
        int row = rr + 8 * q + 4 * kh;
        size_t m = (size_t)(b0 + wm * 32 + row);
        int n0 = wn * 64 + (lane & 31);
        float z0 = accb[0][reg] + pb0f[rr];
        float z1 = accb[1][reg] + pb1f[rr];
        float o0 = z0 / (1.0f + __expf(-z0)) + accs[0][reg] + ps0f[rr];
        float o1 = z1 / (1.0f + __expf(-z1)) + accs[1][reg] + ps1f[rr];
        out[m * 128 + n0] = o0;
        out[m * 128 + n0 + 32] = o1;
      }
    }
    __syncthreads();
  }
}

extern "C" void kernel_launch(void* const* d_in, const int* in_sizes, int n_in,
                              void* d_out, int out_size, void* d_ws, size_t ws_size,
                              hipStream_t stream) {
  const float* x  = (const float*)d_in[0];   // [16384][1024] f32
  const float* wb = (const float*)d_in[1];   // [1024][128]   f32
  const float* ws = (const float*)d_in[2];   // [1024][128][8] f32
  u16* wst3 = (u16*)d_ws;                    // [64][1536] granules, 1.5 MB
  float* out = (float*)d_out;                // [16384][128]  f32

  kan_prep<<<dim3(64), 256, 0, stream>>>(wb, ws, wst3);
  kan_main<<<dim3(256), 512, 0, stream>>>(x, wst3, out);
}

// Round 8
// 136.600 us; speedup vs baseline: 1.1542x; 1.1542x over previous
//
#include <hip/hip_runtime.h>

typedef unsigned short u16;
typedef unsigned int u32;
typedef __bf16 bf16x8 __attribute__((ext_vector_type(8)));
typedef float f32x16 __attribute__((ext_vector_type(16)));

#define C2 (-7.213475204444817f) /* -5/ln2 : exp(-5 t^2) = exp2(C2 t^2) */
#define T1C 0.28650480f          /* e^-1.25 */
#define T2C 0.0067379470f        /* e^-5    */

__device__ __forceinline__ u16 f2bf(float f) {
  u32 u = __float_as_uint(f);
  return (u16)((u + 0x7FFFu + ((u >> 16) & 1u)) >> 16);  // RNE
}

__device__ __forceinline__ f32x16 mfma16(uint4 a, uint4 b, f32x16 c) {
  return __builtin_amdgcn_mfma_f32_32x32x16_bf16(
      __builtin_bit_cast(bf16x8, a), __builtin_bit_cast(bf16x8, b), c, 0, 0, 0);
}

// ---------------------------------------------------------------------------
// Prep (unchanged from R7; validated): f32 weights -> bf16, per-16k-chunk
// fragment order. wst3 granule(c, g) 16 B, g = s*256 + nq*64 + l:
//   content = W_s[k = c*16 + (l>>5)*8 + 0..8)[u = nq*32 + (l&31)]
// ---------------------------------------------------------------------------
__global__ __launch_bounds__(256) void kan_prep(const float* __restrict__ wb,
                                                const float* __restrict__ ws,
                                                u16* __restrict__ wst3) {
  __shared__ u16 tile[6][16][130];
  const int t = threadIdx.x;
  const int c = blockIdx.x;
#pragma unroll
  for (int it = 0; it < 8; ++it) {
    int idx = it * 256 + t;
    int d = idx >> 7, u = idx & 127;
    size_t base = (size_t)(c * 16 + d) * 128 + u;
    const float* p = ws + base * 8;
    float4 v0 = *(const float4*)p;
    float g4 = p[4];
    tile[0][d][u] = f2bf(v0.x);
    tile[1][d][u] = f2bf(v0.y);
    tile[2][d][u] = f2bf(v0.z);
    tile[3][d][u] = f2bf(v0.w);
    tile[4][d][u] = f2bf(g4);
    tile[5][d][u] = f2bf(wb[base]);
  }
  __syncthreads();
#pragma unroll
  for (int i = 0; i < 6; ++i) {
    int g = i * 256 + t;
    int s = g >> 8, r = g & 255;
    int nq = r >> 6, l = r & 63;
    int u = nq * 32 + (l & 31);
    int dbase = (l >> 5) * 8;
    u32 q[4];
#pragma unroll
    for (int j = 0; j < 4; ++j) {
      u32 lo = tile[s][dbase + 2 * j][u];
      u32 hi = tile[s][dbase + 2 * j + 1][u];
      q[j] = lo | (hi << 16);
    }
    uint4 w4; w4.x = q[0]; w4.y = q[1]; w4.z = q[2]; w4.w = q[3];
    *(uint4*)(wst3 + (size_t)c * 12288 + (size_t)g * 8) = w4;
  }
}

// ---------------------------------------------------------------------------
// Main R8: B DIRECT FROM GLOBAL (wst3 is fragment-ordered: one coalesced
// global_load_dwordx4 per B fragment — no LDS staging, no DMA drain at
// barriers; per-wave vmcnt pipelining).  LDS holds only A (rbf), dbuf
// 2 x 48 KB.  grid 256, 512 thr = 8 waves (kq 0..3 = c16-within-BK64,
// wn 0..1 = n-half), wave tile 64m x 64n (acc 8 x f32x16).  16 bodies of
// BK=64, ONE barrier each.  k-partials merged in LDS epilogue.
// A granule-set (s, g=m-half, p=c16): base = (s*8+g*4+p)*1024; lane l reads
// kh=l>>5 at +kh*512, slot (l&31)^(p*2+kh) at slot*16 (XOR-swizzle: writer
// thread (r=t>>3, o=t&7) writes 16 B at slot (r&31)^o -> 8 lanes/bank-quad,
// optimal).  mfma A[m=lane&31][k=(lane>>5)*8+j]; C/D col=lane&31,
// row=(reg&3)+8*(reg>>2)+4*(lane>>5)   (all validated R2-R7).
// ---------------------------------------------------------------------------
__global__ __launch_bounds__(512, 2) void kan_main(const float* __restrict__ x,
                                                   const u16* __restrict__ wst3,
                                                   float* __restrict__ out) {
  __shared__ __align__(16) char lds[98304];  // 2 x 49152

  const int t = threadIdx.x;
  const int lane = t & 63;
  const int w = t >> 6;
  const int kq = w & 3;   // c16 index within BK=64 body
  const int wn = w >> 2;  // n-half
  const int b0 = blockIdx.x * 64;

  // acc[0..3] spline (g*2+nt), acc[4..7] base (g*2+nt)
  f32x16 acc[8];
#pragma unroll
  for (int i = 0; i < 8; ++i)
#pragma unroll
    for (int j = 0; j < 16; ++j) acc[i][j] = 0.f;

  // ---- rbf writer: thread t owns x row r, k-octet o of each BK=64 chunk
  const int r = t >> 3, o = t & 7;
  const float* xp = x + (size_t)(b0 + r) * 1024 + o * 8;
  const u32 aw = (u32)((((r >> 5) * 4 + (o >> 1)) << 10) + ((o & 1) << 9) +
                       (((r & 31) ^ o) << 4));  // + s*8192 (+ buf)

  // ---- B source (byte): + i*98304 + s*4096 + nt*1024
  const char* bsrc = (const char*)wst3 + kq * 24576 + wn * 2048 + lane * 16;

  // ---- A reader (byte): + s*8192 + g*4096 (+ buf)
  const u32 ar = (u32)((kq << 10) + ((lane >> 5) << 9) +
                       ((((lane & 31) ^ (kq * 2 + (lane >> 5)))) << 4));

  auto rbf_write = [&](char* buf, float4 xa, float4 xb) {
    float xf[8] = {xa.x, xa.y, xa.z, xa.w, xb.x, xb.y, xb.z, xb.w};
    u32 pk[6][4];
#pragma unroll
    for (int pp = 0; pp < 4; ++pp) {
      u32 lo6[6], hi6[6];
#pragma unroll
      for (int e = 0; e < 2; ++e) {
        float xv = xf[2 * pp + e];
        float t0 = C2 * xv;
        float P = __builtin_amdgcn_exp2f(t0 * xv);  // e^{-5x^2}
        float Qp = __builtin_amdgcn_exp2f(-t0);     // e^{+5x}
        float Qm = __builtin_amdgcn_exp2f(t0);      // e^{-5x}
        float PQ = P * Qp, PQm = P * Qm;
        u32* dst = e ? hi6 : lo6;
        dst[0] = __float_as_uint(PQm * Qm * T2C) + 0x8000u;
        dst[1] = __float_as_uint(PQm * T1C) + 0x8000u;
        dst[2] = __float_as_uint(P) + 0x8000u;
        dst[3] = __float_as_uint(PQ * T1C) + 0x8000u;
        dst[4] = __float_as_uint(PQ * Qp * T2C) + 0x8000u;
        dst[5] = __float_as_uint(xv) + 0x8000u;
      }
#pragma unroll
      for (int s = 0; s < 6; ++s)
        pk[s][pp] = __builtin_amdgcn_perm(hi6[s], lo6[s], 0x07060302);
    }
#pragma unroll
    for (int s = 0; s < 6; ++s) {
      uint4 v; v.x = pk[s][0]; v.y = pk[s][1]; v.z = pk[s][2]; v.w = pk[s][3];
      *(uint4*)(buf + s * 8192 + aw) = v;
    }
  };

  // ---- prologue: rbf chunk 0 into buf0; prefetch x for chunk 1
  float4 xc0 = *(const float4*)(xp);
  float4 xc1 = *(const float4*)(xp + 4);
  rbf_write(lds, xc0, xc1);
  xc0 = *(const float4*)(xp + 64);
  xc1 = *(const float4*)(xp + 68);
  __syncthreads();

  for (int i = 0; i < 16; ++i) {
    char* cur = lds + (size_t)(i & 1) * 49152;
    char* nxt = lds + (size_t)((i + 1) & 1) * 49152;
    const char* bc = bsrc + (size_t)i * 98304;

    uint4 av[6], bv[6];
    // ---- half 0: subs 0..2 (issue loads, then rbf covers latency, then mfma)
#pragma unroll
    for (int s = 0; s < 3; ++s) {
      bv[2 * s] = *(const uint4*)(bc + s * 4096);
      bv[2 * s + 1] = *(const uint4*)(bc + s * 4096 + 1024);
      av[2 * s] = *(const uint4*)(cur + s * 8192 + ar);
      av[2 * s + 1] = *(const uint4*)(cur + s * 8192 + 4096 + ar);
    }
    if (i < 15) {
      rbf_write(nxt, xc0, xc1);
      if (i < 14) {
        xc0 = *(const float4*)(xp + (i + 2) * 64);
        xc1 = *(const float4*)(xp + (i + 2) * 64 + 4);
      }
    }
#pragma unroll
    for (int s = 0; s < 3; ++s) {
      acc[0] = mfma16(av[2 * s], bv[2 * s], acc[0]);
      acc[1] = mfma16(av[2 * s], bv[2 * s + 1], acc[1]);
      acc[2] = mfma16(av[2 * s + 1], bv[2 * s], acc[2]);
      acc[3] = mfma16(av[2 * s + 1], bv[2 * s + 1], acc[3]);
    }
    // ---- half 1: subs 3..5 (5 = base path -> acc[4..7])
#pragma unroll
    for (int s = 3; s < 6; ++s) {
      int j = 2 * (s - 3);
      bv[j] = *(const uint4*)(bc + s * 4096);
      bv[j + 1] = *(const uint4*)(bc + s * 4096 + 1024);
      av[j] = *(const uint4*)(cur + s * 8192 + ar);
      av[j + 1] = *(const uint4*)(cur + s * 8192 + 4096 + ar);
    }
#pragma unroll
    for (int s = 3; s < 5; ++s) {
      int j = 2 * (s - 3);
      acc[0] = mfma16(av[j], bv[j], acc[0]);
      acc[1] = mfma16(av[j], bv[j + 1], acc[1]);
      acc[2] = mfma16(av[j + 1], bv[j], acc[2]);
      acc[3] = mfma16(av[j + 1], bv[j + 1], acc[3]);
    }
    acc[4] = mfma16(av[4], bv[4], acc[4]);
    acc[5] = mfma16(av[4], bv[5], acc[5]);
    acc[6] = mfma16(av[5], bv[4], acc[6]);
    acc[7] = mfma16(av[5], bv[5], acc[7]);
    __syncthreads();
  }

  // ---- epilogue: 4 rounds; round q merges slot pair (spline q, base 4+q)
  // across kq=1..3 into kq=0, then silu+add+store.
#pragma unroll
  for (int q = 0; q < 4; ++q) {
    if (kq != 0) {
      char* slab = lds + ((kq - 1) * 2 + wn) * 8192;
#pragma unroll
      for (int rq = 0; rq < 4; ++rq) {
        *(float4*)(slab + rq * 1024 + lane * 16) =
            make_float4(acc[q][4 * rq], acc[q][4 * rq + 1],
                        acc[q][4 * rq + 2], acc[q][4 * rq + 3]);
        *(float4*)(slab + 4096 + rq * 1024 + lane * 16) =
            make_float4(acc[4 + q][4 * rq], acc[4 + q][4 * rq + 1],
                        acc[4 + q][4 * rq + 2], acc[4 + q][4 * rq + 3]);
      }
    }
    __syncthreads();
    if (kq == 0) {
#pragma unroll
      for (int p = 1; p < 4; ++p) {
        const char* slab = lds + ((p - 1) * 2 + wn) * 8192;
#pragma unroll
        for (int rq = 0; rq < 4; ++rq) {
          float4 vs = *(const float4*)(slab + rq * 1024 + lane * 16);
          float4 vb = *(const float4*)(slab + 4096 + rq * 1024 + lane * 16);
          acc[q][4 * rq] += vs.x; acc[q][4 * rq + 1] += vs.y;
          acc[q][4 * rq + 2] += vs.z; acc[q][4 * rq + 3] += vs.w;
          acc[4 + q][4 * rq] += vb.x; acc[4 + q][4 * rq + 1] += vb.y;
          acc[4 + q][4 * rq + 2] += vb.z; acc[4 + q][4 * rq + 3] += vb.w;
        }
      }
      const int col = wn * 64 + (q & 1) * 32 + (lane & 31);
#pragma unroll
      for (int reg = 0; reg < 16; ++reg) {
        int row = (q >> 1) * 32 + (reg & 3) + 8 * (reg >> 2) + 4 * (lane >> 5);
        float z = acc[4 + q][reg];
        float sv = z / (1.0f + __expf(-z));
        out[(size_t)(b0 + row) * 128 + col] = sv + acc[q][reg];
      }
    }
    __syncthreads();
  }
}

extern "C" void kernel_launch(void* const* d_in, const int* in_sizes, int n_in,
                              void* d_out, int out_size, void* d_ws, size_t ws_size,
                              hipStream_t stream) {
  const float* x  = (const float*)d_in[0];   // [16384][1024] f32
  const float* wb = (const float*)d_in[1];   // [1024][128]   f32
  const float* ws = (const float*)d_in[2];   // [1024][128][8] f32
  u16* wst3 = (u16*)d_ws;                    // [64][1536] granules, 1.5 MB
  float* out = (float*)d_out;                // [16384][128]  f32

  kan_prep<<<dim3(64), 256, 0, stream>>>(wb, ws, wst3);
  kan_main<<<dim3(256), 512, 0, stream>>>(x, wst3, out);
}